// Round 9
// baseline (227.662 us; speedup 1.0000x reference)
//
#include <hip/hip_runtime.h>
#include <hip/hip_bf16.h>
#include <math.h>

#define NN 8192
#define QSCALE (0.125f * 1.44269504088896f)   // fold 0.125 and log2(e) into Q
#define OSZ (8192*64)
#define NSL 32                                 // pass2 output slices (16 j x 2 tih)

typedef __attribute__((ext_vector_type(8))) short short8;
typedef __attribute__((ext_vector_type(16))) float f32x16;
typedef __attribute__((ext_vector_type(4))) float f32x4;

union W4 { unsigned u[4]; short8 v; };

__device__ inline unsigned short f2bf(float x) {
  union { float f; unsigned u; } t; t.f = x;
  unsigned r = t.u + 0x7fffu + ((t.u >> 16) & 1u);
  return (unsigned short)(r >> 16);
}
__device__ inline unsigned cvtpk(float lo, float hi) {
  unsigned r;
  asm("v_cvt_pk_bf16_f32 %0, %1, %2" : "=v"(r) : "v"(lo), "v"(hi));
  return r;
}
__device__ inline float fexp2(float x) {
  float r;
  asm("v_exp_f32 %0, %1" : "=v"(r) : "v"(x));
  return r;
}
__device__ inline f32x4 ntload4(const float* p) {
  return __builtin_nontemporal_load((const f32x4*)p);
}

// ---------------------------------------------------------------------------
// Kernel 1: Q/K/V/H pre-pack.
//  QP[c8][i][e] = Q[i][c8*8+e]*QSCALE ; KP same for K
//  VP[j8][d][e] = V[j8*8+e][d] ; HP same for H
// ---------------------------------------------------------------------------
__global__ __launch_bounds__(256) void qkv_kernel(
    const float* __restrict__ X, const float* __restrict__ H,
    const float* __restrict__ Qw, const float* __restrict__ Qb,
    const float* __restrict__ Kw, const float* __restrict__ Kb,
    const float* __restrict__ Vw, const float* __restrict__ Vb,
    const float* __restrict__ bng, const float* __restrict__ bnb,
    const float* __restrict__ bnm, const float* __restrict__ bnv,
    unsigned short* __restrict__ QP, unsigned short* __restrict__ KP,
    unsigned short* __restrict__ VP, unsigned short* __restrict__ HP)
{
  int wid = (blockIdx.x * blockDim.x + threadIdx.x) >> 6; // 0..2047
  int d = threadIdx.x & 63;
  float4 w[16];

  for (int fq = 0; fq < 16; fq++) w[fq] = *(const float4*)(Qw + d*64 + fq*4);
  for (int rr = 0; rr < 4; rr++) {
    int r = wid*4 + rr;
    float a = Qb[d];
    for (int fq = 0; fq < 16; fq++) {
      float4 xv = *(const float4*)(X + r*64 + fq*4);
      a += w[fq].x*xv.x + w[fq].y*xv.y + w[fq].z*xv.z + w[fq].w*xv.w;
    }
    float s = a;
    for (int off = 32; off; off >>= 1) s += __shfl_xor(s, off);
    float mean = s * (1.f/64.f);
    float c = a - mean;
    float s2 = c*c;
    for (int off = 32; off; off >>= 1) s2 += __shfl_xor(s2, off);
    float q = c * rsqrtf(s2*(1.f/64.f) + 1e-5f);
    QP[(d>>3)*65536 + r*8 + (d&7)] = f2bf(q * QSCALE);
  }
  for (int fq = 0; fq < 16; fq++) w[fq] = *(const float4*)(Kw + d*64 + fq*4);
  for (int rr = 0; rr < 4; rr++) {
    int r = wid*4 + rr;
    float a = Kb[d];
    for (int fq = 0; fq < 16; fq++) {
      float4 hv = *(const float4*)(H + r*64 + fq*4);
      a += w[fq].x*hv.x + w[fq].y*hv.y + w[fq].z*hv.z + w[fq].w*hv.w;
    }
    float s = a;
    for (int off = 32; off; off >>= 1) s += __shfl_xor(s, off);
    float mean = s * (1.f/64.f);
    float c = a - mean;
    float s2 = c*c;
    for (int off = 32; off; off >>= 1) s2 += __shfl_xor(s2, off);
    float k = c * rsqrtf(s2*(1.f/64.f) + 1e-5f);
    KP[(d>>3)*65536 + r*8 + (d&7)] = f2bf(k);
  }
  for (int fq = 0; fq < 16; fq++) w[fq] = *(const float4*)(Vw + d*64 + fq*4);
  float bscale = rsqrtf(bnv[d] + 1e-5f) * bng[d];
  for (int rr = 0; rr < 4; rr++) {
    int r = wid*4 + rr;
    float a = Vb[d];
    for (int fq = 0; fq < 16; fq++) {
      float4 hv = *(const float4*)(H + r*64 + fq*4);
      a += w[fq].x*hv.x + w[fq].y*hv.y + w[fq].z*hv.z + w[fq].w*hv.w;
    }
    float v = (a - bnm[d]) * bscale + bnb[d];
    VP[(r>>3)*512 + d*8 + (r&7)] = f2bf(v);
    HP[(r>>3)*512 + d*8 + (r&7)] = f2bf(H[r*64 + d]);
  }
}

// ---------------------------------------------------------------------------
// pass 1 (lean): per-column sums of exp2(s*M). No LDS, no barrier.
// ---------------------------------------------------------------------------
__global__ __launch_bounds__(256) void pass1_kernel(
    const float* __restrict__ M, const unsigned short* __restrict__ QP,
    const unsigned short* __restrict__ KP, float* __restrict__ pd)
{
  int tid = threadIdx.x;
  int wj = (blockIdx.x * blockDim.x + tid) >> 6;  // 0..8191
  int lane = tid & 63;
  int l31 = lane & 31, h = lane >> 5;
  int jb = wj & 255, slice = wj >> 8;             // 256 jb x 32 slices
  int j = jb*32 + l31;

  short8 kb[4];
  for (int m = 0; m < 4; m++)
    kb[m] = *(const short8*)(KP + (2*m + h)*65536 + j*8);

  float Mv[16];
  {
    int i0 = slice*8*32;
#pragma unroll
    for (int r = 0; r < 16; r++) {
      int ir = (r&3) + 8*(r>>2) + 4*h;
      Mv[r] = __builtin_nontemporal_load(M + (size_t)(i0 + ir)*NN + j);
    }
  }

  float d0 = 0.f, d1 = 0.f, d2 = 0.f, d3 = 0.f;
  for (int t = 0; t < 8; t++) {
    int i0 = (slice*8 + t) * 32;
    float Mn[16];
    if (t < 7) {
      int i1 = i0 + 32;
#pragma unroll
      for (int r = 0; r < 16; r++) {
        int ir = (r&3) + 8*(r>>2) + 4*h;
        Mn[r] = __builtin_nontemporal_load(M + (size_t)(i1 + ir)*NN + j);
      }
    }

    f32x16 acc;
    for (int r = 0; r < 16; r++) acc[r] = 0.f;
    for (int m = 0; m < 4; m++) {
      short8 qa = *(const short8*)(QP + (2*m + h)*65536 + (size_t)(i0 + l31)*8);
      acc = __builtin_amdgcn_mfma_f32_32x32x16_bf16(qa, kb[m], acc, 0, 0, 0);
    }

    d0 += fexp2(acc[0]*Mv[0]) + fexp2(acc[4]*Mv[4]) + fexp2(acc[8]*Mv[8])   + fexp2(acc[12]*Mv[12]);
    d1 += fexp2(acc[1]*Mv[1]) + fexp2(acc[5]*Mv[5]) + fexp2(acc[9]*Mv[9])   + fexp2(acc[13]*Mv[13]);
    d2 += fexp2(acc[2]*Mv[2]) + fexp2(acc[6]*Mv[6]) + fexp2(acc[10]*Mv[10]) + fexp2(acc[14]*Mv[14]);
    d3 += fexp2(acc[3]*Mv[3]) + fexp2(acc[7]*Mv[7]) + fexp2(acc[11]*Mv[11]) + fexp2(acc[15]*Mv[15]);

    if (t < 7) {
#pragma unroll
      for (int r = 0; r < 16; r++) Mv[r] = Mn[r];
    }
  }
  float drun = (d0 + d1) + (d2 + d3);
  drun += __shfl_xor(drun, 32);
  if (lane < 32) pd[(size_t)slice*NN + j] = drun;
}

// ---------------------------------------------------------------------------
// combine: cc[j] = log2(10 * D_j)
// ---------------------------------------------------------------------------
__global__ __launch_bounds__(256) void combine_kernel(
    const float* __restrict__ pd, float* __restrict__ colcc)
{
  int j = blockIdx.x * blockDim.x + threadIdx.x;
  float Dv = 0.f;
  for (int s = 0; s < 32; s++) Dv += pd[(size_t)s*NN + j];
  colcc[j] = log2f(Dv * 10.f);
}

// ---------------------------------------------------------------------------
// pass 2 (barrier-free, wave-private): wave = (iq = i-half, tih = j-strip).
// Each wave owns a private 32x32 M strip per tm: stages it (bf16-packed)
// into its OWN LDS buffer -- no inter-wave sharing, NO barriers in the loop.
// Wave computes full d=64 (oaccA/oaccB). Staged word doubles as the M@H
// A-frag word. Output: 32 opart slices (slice*2 + tih), reduced later.
// Grid = 128 iblk x 16 slices (512 j each); WG = 4 waves.
// ---------------------------------------------------------------------------
#define MSTW 18   // words per 32-col row (16 data + 2 pad): even -> b64-aligned

__global__ __launch_bounds__(256, 4) void pass2_kernel(
    const float* __restrict__ M, const unsigned short* __restrict__ QP,
    const unsigned short* __restrict__ KP, const unsigned short* __restrict__ VP,
    const unsigned short* __restrict__ HP, const float* __restrict__ colcc,
    float* __restrict__ opart)
{
  __shared__ unsigned mtw[4][2][32*MSTW];
  __shared__ __align__(16) float cls[512];

  int iblk = blockIdx.x >> 4, slice = blockIdx.x & 15;
  int i0 = iblk * 64;
  int tid = threadIdx.x;
  int lane = tid & 63, wv = tid >> 6;
  int l31 = lane & 31, h = lane >> 5;
  int iq = wv & 1, tih = wv >> 1;
  int irow = iq*32 + l31;
  int i_g = i0 + irow;

  short8 qb[4];
  for (int m = 0; m < 4; m++)
    qb[m] = *(const short8*)(QP + (2*m + h)*65536 + (size_t)i_g*8);

  cls[tid]       = colcc[slice*512 + tid];
  cls[tid + 256] = colcc[slice*512 + 256 + tid];
  __syncthreads();   // one-time (cls visibility)

  // wave-private stage map: lane -> (row sr, 16-col half scb)
  int sr = lane >> 1, scb = (lane & 1) * 16;
  const float* gsrc = M + (size_t)(i0 + iq*32 + sr)*NN + slice*512 + tih*32 + scb;
  unsigned* myw0 = &mtw[wv][0][0];
  unsigned* myw1 = &mtw[wv][1][0];
  int wbase = sr*MSTW + (lane & 1)*8;

  // prologue: stage strip 0 into buf0 (wave-local, no barrier)
  {
    f32x4 v0 = ntload4(gsrc);
    f32x4 v1 = ntload4(gsrc + 4);
    f32x4 v2 = ntload4(gsrc + 8);
    f32x4 v3 = ntload4(gsrc + 12);
    uint2 w01 = {cvtpk(v0.x,v0.y), cvtpk(v0.z,v0.w)};
    uint2 w23 = {cvtpk(v1.x,v1.y), cvtpk(v1.z,v1.w)};
    uint2 w45 = {cvtpk(v2.x,v2.y), cvtpk(v2.z,v2.w)};
    uint2 w67 = {cvtpk(v3.x,v3.y), cvtpk(v3.z,v3.w)};
    *(uint2*)(&myw0[wbase + 0]) = w01;
    *(uint2*)(&myw0[wbase + 2]) = w23;
    *(uint2*)(&myw0[wbase + 4]) = w45;
    *(uint2*)(&myw0[wbase + 6]) = w67;
  }

  f32x16 oaccA, oaccB;
  for (int r = 0; r < 16; r++) { oaccA[r] = 0.f; oaccB[r] = 0.f; }

  for (int tm = 0; tm < 8; tm++) {
    int jloc = tm*64 + tih*32;
    int jt = slice*512 + jloc;

    // ---- issue stage loads for strip tm+1 (consumed at bottom) ----
    f32x4 s0, s1, s2, s3;
    if (tm < 7) {
      const float* src = gsrc + (tm+1)*64;
      s0 = ntload4(src);     s1 = ntload4(src + 4);
      s2 = ntload4(src + 8); s3 = ntload4(src + 12);
    }

    // ---- K frags ----
    short8 kb[4];
#pragma unroll
    for (int m = 0; m < 4; m++)
      kb[m] = *(const short8*)(KP + (2*m + h)*65536 + (size_t)(jt + l31)*8);

    // ---- Mv words from private LDS (b64, ~2-way max) ----
    unsigned mvw[8];
    {
      const unsigned* mb = (tm & 1) ? myw1 : myw0;
#pragma unroll
      for (int q = 0; q < 4; q++) {
        uint2 t2 = *(const uint2*)(&mb[l31*MSTW + 4*q + 2*h]);
        mvw[2*q] = t2.x; mvw[2*q+1] = t2.y;
      }
    }

    // ---- sacc = K x Q^T (lane = i, regs = j) ----
    f32x16 sacc;
    for (int r = 0; r < 16; r++) sacc[r] = 0.f;
#pragma unroll
    for (int m = 0; m < 4; m++)
      sacc = __builtin_amdgcn_mfma_f32_32x32x16_bf16(kb[m], qb[m], sacc, 0, 0, 0);

    // ---- p = exp2(s*M - cc) (bf16 M unpacked from staged words) ----
    float p[16];
#pragma unroll
    for (int q = 0; q < 4; q++) {
      float4 cc = *(const float4*)(&cls[jloc + 8*q + 4*h]);
      unsigned wa = mvw[2*q], wb = mvw[2*q + 1];
      float m0 = __uint_as_float(wa << 16);
      float m1 = __uint_as_float(wa & 0xffff0000u);
      float m2 = __uint_as_float(wb << 16);
      float m3 = __uint_as_float(wb & 0xffff0000u);
      p[4*q+0] = fexp2(fmaf(sacc[4*q+0], m0, -cc.x));
      p[4*q+1] = fexp2(fmaf(sacc[4*q+1], m1, -cc.y));
      p[4*q+2] = fexp2(fmaf(sacc[4*q+2], m2, -cc.z));
      p[4*q+3] = fexp2(fmaf(sacc[4*q+3], m3, -cc.w));
    }
    unsigned pu[8];
#pragma unroll
    for (int k = 0; k < 8; k++) pu[k] = cvtpk(p[2*k], p[2*k+1]);

    // ---- half-swaps: P and M words -> A-frag words ----
    asm volatile("v_permlane32_swap_b32 %0, %1" : "+v"(pu[0]), "+v"(pu[2]));
    asm volatile("v_permlane32_swap_b32 %0, %1" : "+v"(pu[1]), "+v"(pu[3]));
    asm volatile("v_permlane32_swap_b32 %0, %1" : "+v"(pu[4]), "+v"(pu[6]));
    asm volatile("v_permlane32_swap_b32 %0, %1" : "+v"(pu[5]), "+v"(pu[7]));
    asm volatile("v_permlane32_swap_b32 %0, %1" : "+v"(mvw[0]), "+v"(mvw[2]));
    asm volatile("v_permlane32_swap_b32 %0, %1" : "+v"(mvw[1]), "+v"(mvw[3]));
    asm volatile("v_permlane32_swap_b32 %0, %1" : "+v"(mvw[4]), "+v"(mvw[6]));
    asm volatile("v_permlane32_swap_b32 %0, %1" : "+v"(mvw[5]), "+v"(mvw[7]));

    W4 PA0, PA1, MA0, MA1;
    PA0.u[0] = pu[0];  PA0.u[1] = pu[1];  PA0.u[2] = pu[2];  PA0.u[3] = pu[3];
    PA1.u[0] = pu[4];  PA1.u[1] = pu[5];  PA1.u[2] = pu[6];  PA1.u[3] = pu[7];
    MA0.u[0] = mvw[0]; MA0.u[1] = mvw[1]; MA0.u[2] = mvw[2]; MA0.u[3] = mvw[3];
    MA1.u[0] = mvw[4]; MA1.u[1] = mvw[5]; MA1.u[2] = mvw[6]; MA1.u[3] = mvw[7];

    // ---- output MFMAs, d-half A then d-half B (limits live V/H regs) ----
    int j8 = jt >> 3;
    const unsigned short* vb_ = VP + (size_t)j8*512 + l31*8;
    const unsigned short* hb_ = HP + (size_t)j8*512 + l31*8;
    {
      short8 vA1 = *(const short8*)(vb_ + h*512);
      short8 vA2 = *(const short8*)(vb_ + (2 + h)*512);
      short8 hA1 = *(const short8*)(hb_ + h*512);
      short8 hA2 = *(const short8*)(hb_ + (2 + h)*512);
      oaccA = __builtin_amdgcn_mfma_f32_32x32x16_bf16(PA0.v, vA1, oaccA, 0, 0, 0);
      oaccA = __builtin_amdgcn_mfma_f32_32x32x16_bf16(PA1.v, vA2, oaccA, 0, 0, 0);
      oaccA = __builtin_amdgcn_mfma_f32_32x32x16_bf16(MA0.v, hA1, oaccA, 0, 0, 0);
      oaccA = __builtin_amdgcn_mfma_f32_32x32x16_bf16(MA1.v, hA2, oaccA, 0, 0, 0);
    }
    {
      short8 vB1 = *(const short8*)(vb_ + 256 + h*512);       // d 32..63: +32*8
      short8 vB2 = *(const short8*)(vb_ + 256 + (2 + h)*512);
      short8 hB1 = *(const short8*)(hb_ + 256 + h*512);
      short8 hB2 = *(const short8*)(hb_ + 256 + (2 + h)*512);
      oaccB = __builtin_amdgcn_mfma_f32_32x32x16_bf16(PA0.v, vB1, oaccB, 0, 0, 0);
      oaccB = __builtin_amdgcn_mfma_f32_32x32x16_bf16(PA1.v, vB2, oaccB, 0, 0, 0);
      oaccB = __builtin_amdgcn_mfma_f32_32x32x16_bf16(MA0.v, hB1, oaccB, 0, 0, 0);
      oaccB = __builtin_amdgcn_mfma_f32_32x32x16_bf16(MA1.v, hB2, oaccB, 0, 0, 0);
    }

    // ---- write-late: pack + store staged strip to the other buffer ----
    if (tm < 7) {
      unsigned* dst = ((tm+1) & 1) ? myw1 : myw0;
      uint2 w01 = {cvtpk(s0.x,s0.y), cvtpk(s0.z,s0.w)};
      uint2 w23 = {cvtpk(s1.x,s1.y), cvtpk(s1.z,s1.w)};
      uint2 w45 = {cvtpk(s2.x,s2.y), cvtpk(s2.z,s2.w)};
      uint2 w67 = {cvtpk(s3.x,s3.y), cvtpk(s3.z,s3.w)};
      *(uint2*)(&dst[wbase + 0]) = w01;
      *(uint2*)(&dst[wbase + 2]) = w23;
      *(uint2*)(&dst[wbase + 4]) = w45;
      *(uint2*)(&dst[wbase + 6]) = w67;
    }
    // no barrier: buffers are wave-private
  }

  float* obase = opart + (size_t)(slice*2 + tih)*OSZ;
#pragma unroll
  for (int r = 0; r < 16; r++) {
    int orow = i0 + iq*32 + (r&3) + 8*(r>>2) + 4*h;
    obase[(size_t)orow*64 + l31]      = oaccA[r];
    obase[(size_t)orow*64 + 32 + l31] = oaccB[r];
  }
}

// ---------------------------------------------------------------------------
// reduce: out = sum over NSL slices of opart  (float4, fully coalesced)
// ---------------------------------------------------------------------------
__global__ __launch_bounds__(256) void reduce_kernel(
    const float* __restrict__ opart, float* __restrict__ out)
{
  int e4 = blockIdx.x * blockDim.x + threadIdx.x;   // 0..131071
  const float4* p = (const float4*)opart;
  float4 a = p[e4];
#pragma unroll
  for (int s = 1; s < NSL; s++) {
    float4 b = p[(size_t)s*(OSZ/4) + e4];
    a.x += b.x; a.y += b.y; a.z += b.z; a.w += b.w;
  }
  ((float4*)out)[e4] = a;
}

// ---------------------------------------------------------------------------
extern "C" void kernel_launch(void* const* d_in, const int* in_sizes, int n_in,
                              void* d_out, int out_size, void* d_ws, size_t ws_size,
                              hipStream_t stream) {
  const float* X   = (const float*)d_in[0];
  const float* H   = (const float*)d_in[1];
  const float* M   = (const float*)d_in[2];
  const float* Qw  = (const float*)d_in[3];
  const float* Qb  = (const float*)d_in[4];
  const float* Kw  = (const float*)d_in[5];
  const float* Kb  = (const float*)d_in[6];
  const float* Vw  = (const float*)d_in[7];
  const float* Vb  = (const float*)d_in[8];
  const float* bng = (const float*)d_in[9];
  const float* bnb = (const float*)d_in[10];
  const float* bnm = (const float*)d_in[11];
  const float* bnv = (const float*)d_in[12];
  float* out = (float*)d_out;

  char* ws = (char*)d_ws;
  const size_t MB = 1024*1024;
  unsigned short* QP  = (unsigned short*)(ws);           // 1 MB
  unsigned short* KP  = (unsigned short*)(ws + 1*MB);
  unsigned short* VP  = (unsigned short*)(ws + 2*MB);
  unsigned short* HP  = (unsigned short*)(ws + 3*MB);
  float* pd           = (float*)(ws + 4*MB);             // 1 MB
  float* colcc        = (float*)(ws + 5*MB);             // 32 KB
  float* opart        = (float*)(ws + 6*MB);             // 64 MB (32 slices)

  qkv_kernel<<<512, 256, 0, stream>>>(X, H, Qw, Qb, Kw, Kb, Vw, Vb,
                                      bng, bnb, bnm, bnv, QP, KP, VP, HP);
  pass1_kernel<<<2048, 256, 0, stream>>>(M, QP, KP, pd);
  combine_kernel<<<32, 256, 0, stream>>>(pd, colcc);
  pass2_kernel<<<2048, 256, 0, stream>>>(M, QP, KP, VP, HP, colcc, opart);
  reduce_kernel<<<512, 256, 0, stream>>>(opart, out);
}